// Round 2
// baseline (800.930 us; speedup 1.0000x reference)
//
#include <hip/hip_runtime.h>
#include <hip/hip_bf16.h>
#include <stdint.h>

#define MDIM 8192
#define NDIM 4096
#define KDIM 4096

#define BM 128
#define BN 128
#define BK 64

typedef short bf16x8 __attribute__((ext_vector_type(8)));
typedef float floatx4 __attribute__((ext_vector_type(4)));

__device__ __forceinline__ unsigned short f2bf(float f) {
    union { __hip_bfloat16 h; unsigned short u; } v;
    v.h = __float2bfloat16(f);
    return v.u;
}

// ---------- fp32 -> bf16 bulk convert (8 elements / thread / iter) ----------
__global__ __launch_bounds__(256) void cvt_bf16(
    const float* __restrict__ in, unsigned short* __restrict__ out, int n8) {
    int idx = blockIdx.x * blockDim.x + threadIdx.x;
    int stride = gridDim.x * blockDim.x;
    for (int i = idx; i < n8; i += stride) {
        const float4* p = (const float4*)in + (size_t)i * 2;
        float4 a = p[0], b = p[1];
        bf16x8 o;
        o[0] = (short)f2bf(a.x); o[1] = (short)f2bf(a.y);
        o[2] = (short)f2bf(a.z); o[3] = (short)f2bf(a.w);
        o[4] = (short)f2bf(b.x); o[5] = (short)f2bf(b.y);
        o[6] = (short)f2bf(b.z); o[7] = (short)f2bf(b.w);
        *((bf16x8*)out + i) = o;
    }
}

// ---------- xa[m,r] = (1/16) * sum_k x[m,k]*A[r,k]  (fp32 in, bf16 out) ----
// Also converts B [4096,16] fp32 -> bf16 (first 8192 global threads).
__global__ __launch_bounds__(256) void lora_xa(
    const float* __restrict__ x,
    const float* __restrict__ A,
    const float* __restrict__ Bf,
    unsigned short* __restrict__ xa,
    unsigned short* __restrict__ Bc) {
    const int gt = blockIdx.x * blockDim.x + threadIdx.x;
    // B convert: 4096*16 = 65536 elements = 8192 chunks of 8
    if (gt < 8192) {
        const float4* p = (const float4*)Bf + (size_t)gt * 2;
        float4 a = p[0], b = p[1];
        bf16x8 o;
        o[0] = (short)f2bf(a.x); o[1] = (short)f2bf(a.y);
        o[2] = (short)f2bf(a.z); o[3] = (short)f2bf(a.w);
        o[4] = (short)f2bf(b.x); o[5] = (short)f2bf(b.y);
        o[6] = (short)f2bf(b.z); o[7] = (short)f2bf(b.w);
        *((bf16x8*)Bc + gt) = o;
    }

    const int lane = threadIdx.x & 63;
    const int wave = gt >> 6;
    const int nw = (gridDim.x * blockDim.x) >> 6;

    for (int m = wave; m < MDIM; m += nw) {
        float acc[16];
#pragma unroll
        for (int r = 0; r < 16; ++r) acc[r] = 0.f;

        for (int k = lane * 4; k < KDIM; k += 64 * 4) {
            float4 xv = *(const float4*)(x + (size_t)m * KDIM + k);
#pragma unroll
            for (int r = 0; r < 16; ++r) {
                float4 av = *(const float4*)(A + (size_t)r * KDIM + k);
                acc[r] += xv.x * av.x + xv.y * av.y + xv.z * av.z + xv.w * av.w;
            }
        }
#pragma unroll
        for (int r = 0; r < 16; ++r) {
#pragma unroll
            for (int off = 32; off > 0; off >>= 1)
                acc[r] += __shfl_xor(acc[r], off, 64);
        }
        if (lane == 0) {
            const float scale = 1.0f / 16.0f;
#pragma unroll
            for (int r = 0; r < 16; ++r)
                xa[(size_t)m * 16 + r] = f2bf(acc[r] * scale);
        }
    }
}

// ---------- m97-style 128x128 bf16 GEMM + fused LoRA MFMA + fp32 bias ------
// out[m,n] = sum_k x[m,k] W[n,k] + bias[n] + sum_r xa[m,r] * B[n,r]
__global__ __launch_bounds__(256, 1) void lora_gemm(
    const unsigned short* __restrict__ x,   // [M,K] bf16
    const unsigned short* __restrict__ W,   // [N,K] bf16
    const float* __restrict__ bias,         // [N] fp32
    const unsigned short* __restrict__ Bl,  // [N,16] bf16
    const unsigned short* __restrict__ xa,  // [M,16] bf16 (prescaled)
    float* __restrict__ out) {              // [M,N] fp32
    __shared__ __align__(16) unsigned short lA[BM * BK];
    __shared__ __align__(16) unsigned short lB[BN * BK];
    __shared__ __align__(16) unsigned short lLA[BM * 32];
    __shared__ __align__(16) unsigned short lLB[BN * 32];

    const int bn = blockIdx.x * BN;
    const int bm = blockIdx.y * BM;
    const int t = threadIdx.x;
    const int lane = t & 63;
    const int wave = t >> 6;
    const int wm = (wave >> 1) * 64;
    const int wn = (wave & 1) * 64;
    const int fr = lane & 15;
    const int fq = lane >> 4;

    // Stage LoRA rank-16 tiles once per block (zero-padded to K=32).
    {
        int lrow = t & 127;
        if (t < 128) {
            *(bf16x8*)&lLA[lrow * 32]     = *(const bf16x8*)(xa + (size_t)(bm + lrow) * 16);
            *(bf16x8*)&lLA[lrow * 32 + 8] = *(const bf16x8*)(xa + (size_t)(bm + lrow) * 16 + 8);
            *(bf16x8*)&lLB[lrow * 32]     = *(const bf16x8*)(Bl + (size_t)(bn + lrow) * 16);
            *(bf16x8*)&lLB[lrow * 32 + 8] = *(const bf16x8*)(Bl + (size_t)(bn + lrow) * 16 + 8);
        } else {
            bf16x8 z = {0, 0, 0, 0, 0, 0, 0, 0};
            *(bf16x8*)&lLA[lrow * 32 + 16] = z;
            *(bf16x8*)&lLA[lrow * 32 + 24] = z;
            *(bf16x8*)&lLB[lrow * 32 + 16] = z;
            *(bf16x8*)&lLB[lrow * 32 + 24] = z;
        }
    }

    floatx4 acc[4][4];
#pragma unroll
    for (int i = 0; i < 4; ++i)
#pragma unroll
        for (int j = 0; j < 4; ++j)
            acc[i][j] = (floatx4){0.f, 0.f, 0.f, 0.f};

    for (int k0 = 0; k0 < KDIM; k0 += BK) {
#pragma unroll
        for (int i = 0; i < 4; ++i) {
            int cbase = i * 256 + wave * 64;
            int c = cbase + lane;
            int row = c >> 3;
            int cc = c & 7;
            __builtin_amdgcn_global_load_lds(
                (const __attribute__((address_space(1))) unsigned int*)(x + (size_t)(bm + row) * KDIM + k0 + cc * 8),
                (__attribute__((address_space(3))) unsigned int*)&lA[cbase * 8], 16, 0, 0);
            __builtin_amdgcn_global_load_lds(
                (const __attribute__((address_space(1))) unsigned int*)(W + (size_t)(bn + row) * KDIM + k0 + cc * 8),
                (__attribute__((address_space(3))) unsigned int*)&lB[cbase * 8], 16, 0, 0);
        }
        __syncthreads();

#pragma unroll
        for (int kk = 0; kk < BK; kk += 32) {
            bf16x8 af[4], bfv[4];
#pragma unroll
            for (int i = 0; i < 4; ++i)
                af[i] = *(const bf16x8*)&lA[(wm + i * 16 + fr) * BK + kk + fq * 8];
#pragma unroll
            for (int j = 0; j < 4; ++j)
                bfv[j] = *(const bf16x8*)&lB[(wn + j * 16 + fr) * BK + kk + fq * 8];
#pragma unroll
            for (int i = 0; i < 4; ++i)
#pragma unroll
                for (int j = 0; j < 4; ++j)
                    acc[i][j] = __builtin_amdgcn_mfma_f32_16x16x32_bf16(af[i], bfv[j], acc[i][j], 0, 0, 0);
        }
        __syncthreads();
    }

    // LoRA delta: one extra rank-16 (zero-padded K=32) MFMA step.
    {
        bf16x8 af[4], bfv[4];
#pragma unroll
        for (int i = 0; i < 4; ++i)
            af[i] = *(const bf16x8*)&lLA[(wm + i * 16 + fr) * 32 + fq * 8];
#pragma unroll
        for (int j = 0; j < 4; ++j)
            bfv[j] = *(const bf16x8*)&lLB[(wn + j * 16 + fr) * 32 + fq * 8];
#pragma unroll
        for (int i = 0; i < 4; ++i)
#pragma unroll
            for (int j = 0; j < 4; ++j)
                acc[i][j] = __builtin_amdgcn_mfma_f32_16x16x32_bf16(af[i], bfv[j], acc[i][j], 0, 0, 0);
    }

    // Epilogue: D layout col=lane&15, row=(lane>>4)*4+reg. Add fp32 bias, store fp32.
#pragma unroll
    for (int j = 0; j < 4; ++j) {
        int col = bn + wn + j * 16 + fr;
        float bv = bias[col];
#pragma unroll
        for (int i = 0; i < 4; ++i) {
            int row0 = bm + wm + i * 16 + fq * 4;
#pragma unroll
            for (int r = 0; r < 4; ++r) {
                out[(size_t)(row0 + r) * NDIM + col] = acc[i][j][r] + bv;
            }
        }
    }
}

extern "C" void kernel_launch(void* const* d_in, const int* in_sizes, int n_in,
                              void* d_out, int out_size, void* d_ws, size_t ws_size,
                              hipStream_t stream) {
    const float* x    = (const float*)d_in[0];  // [4,2048,4096] fp32
    const float* W    = (const float*)d_in[1];  // [4096,4096] fp32
    const float* bias = (const float*)d_in[2];  // [4096] fp32
    const float* A    = (const float*)d_in[3];  // [16,4096] fp32
    const float* Bf   = (const float*)d_in[4];  // [4096,16] fp32
    float* out = (float*)d_out;                 // [8192,4096] fp32

    // Workspace layout (bytes):
    //   [0,           64 MB)  xc  : x as bf16  [8192,4096]
    //   [64 MB,       96 MB)  Wc  : W as bf16  [4096,4096]
    //   [96 MB,    +256 KB)   xa  : bf16 [8192,16] (prescaled by 1/16)
    //   [.. ,      +128 KB)   Bc  : bf16 [4096,16]
    unsigned short* xc = (unsigned short*)d_ws;
    unsigned short* Wc = xc + (size_t)MDIM * KDIM;
    unsigned short* xa = Wc + (size_t)NDIM * KDIM;
    unsigned short* Bc = xa + (size_t)MDIM * 16;

    cvt_bf16<<<8192, 256, 0, stream>>>(x, xc, (MDIM * KDIM) / 8);
    cvt_bf16<<<4096, 256, 0, stream>>>(W, Wc, (NDIM * KDIM) / 8);
    lora_xa<<<256, 256, 0, stream>>>(x, A, Bf, xa, Bc);
    lora_gemm<<<dim3(NDIM / BN, MDIM / BM), 256, 0, stream>>>(xc, Wc, bias, Bc, xa, out);
}

// Round 3
// 557.068 us; speedup vs baseline: 1.4378x; 1.4378x over previous
//
#include <hip/hip_runtime.h>
#include <hip/hip_bf16.h>
#include <stdint.h>

#define MDIM 8192
#define NDIM 4096
#define KDIM 4096

#define BM 128
#define BN 128
#define BK 64

typedef short bf16x8 __attribute__((ext_vector_type(8)));
typedef float floatx4 __attribute__((ext_vector_type(4)));

__device__ __forceinline__ unsigned short f2bf(float f) {
    union { __hip_bfloat16 h; unsigned short u; } v;
    v.h = __float2bfloat16(f);
    return v.u;
}

__device__ __forceinline__ float bf2f(unsigned short u) {
    union { unsigned int i; float f; } v;
    v.i = ((unsigned int)u) << 16;
    return v.f;
}

// ---------- fp32 -> bf16 bulk convert (8 elements / thread / iter) ----------
__global__ __launch_bounds__(256) void cvt_bf16(
    const float* __restrict__ in, unsigned short* __restrict__ out, int n8) {
    int idx = blockIdx.x * blockDim.x + threadIdx.x;
    int stride = gridDim.x * blockDim.x;
    for (int i = idx; i < n8; i += stride) {
        const float4* p = (const float4*)in + (size_t)i * 2;
        float4 a = p[0], b = p[1];
        bf16x8 o;
        o[0] = (short)f2bf(a.x); o[1] = (short)f2bf(a.y);
        o[2] = (short)f2bf(a.z); o[3] = (short)f2bf(a.w);
        o[4] = (short)f2bf(b.x); o[5] = (short)f2bf(b.y);
        o[6] = (short)f2bf(b.z); o[7] = (short)f2bf(b.w);
        *((bf16x8*)out + i) = o;
    }
}

// ---------- xa[m,r] = (1/16) * sum_k x[m,k]*A[r,k] ----------
// 4 rows per wave (A loads shared across rows). x read from bf16 copy.
// Also converts B [4096,16] fp32 -> bf16 (first 8192 global threads).
__global__ __launch_bounds__(256) void lora_xa(
    const unsigned short* __restrict__ xc,  // [M,K] bf16
    const float* __restrict__ A,            // [16,K] fp32
    const float* __restrict__ Bf,           // [N,16] fp32
    unsigned short* __restrict__ xa,        // [M,16] bf16 out (prescaled)
    unsigned short* __restrict__ Bc) {      // [N,16] bf16 out
    const int gt = blockIdx.x * blockDim.x + threadIdx.x;
    if (gt < 8192) {  // B convert: 65536 elems = 8192 chunks of 8
        const float4* p = (const float4*)Bf + (size_t)gt * 2;
        float4 a = p[0], b = p[1];
        bf16x8 o;
        o[0] = (short)f2bf(a.x); o[1] = (short)f2bf(a.y);
        o[2] = (short)f2bf(a.z); o[3] = (short)f2bf(a.w);
        o[4] = (short)f2bf(b.x); o[5] = (short)f2bf(b.y);
        o[6] = (short)f2bf(b.z); o[7] = (short)f2bf(b.w);
        *((bf16x8*)Bc + gt) = o;
    }

    const int lane = threadIdx.x & 63;
    const int wave = gt >> 6;           // 2048 waves, 4 rows each
    const int m0 = wave * 4;
    if (m0 >= MDIM) return;

    float acc[4][16];
#pragma unroll
    for (int q = 0; q < 4; ++q)
#pragma unroll
        for (int r = 0; r < 16; ++r) acc[q][r] = 0.f;

    for (int k = lane * 4; k < KDIM; k += 256) {
        float xf[4][4];
#pragma unroll
        for (int q = 0; q < 4; ++q) {
            short4 xv = *(const short4*)(xc + (size_t)(m0 + q) * KDIM + k);
            xf[q][0] = bf2f((unsigned short)xv.x);
            xf[q][1] = bf2f((unsigned short)xv.y);
            xf[q][2] = bf2f((unsigned short)xv.z);
            xf[q][3] = bf2f((unsigned short)xv.w);
        }
#pragma unroll
        for (int r = 0; r < 16; ++r) {
            float4 av = *(const float4*)(A + (size_t)r * KDIM + k);
#pragma unroll
            for (int q = 0; q < 4; ++q)
                acc[q][r] += xf[q][0] * av.x + xf[q][1] * av.y +
                             xf[q][2] * av.z + xf[q][3] * av.w;
        }
    }
#pragma unroll
    for (int q = 0; q < 4; ++q)
#pragma unroll
        for (int r = 0; r < 16; ++r) {
#pragma unroll
            for (int off = 32; off > 0; off >>= 1)
                acc[q][r] += __shfl_xor(acc[q][r], off, 64);
        }
    if (lane == 0) {
        const float scale = 1.0f / 16.0f;
#pragma unroll
        for (int q = 0; q < 4; ++q)
#pragma unroll
            for (int r = 0; r < 16; ++r)
                xa[(size_t)(m0 + q) * 16 + r] = f2bf(acc[q][r] * scale);
    }
}

// ---------- 128x128 bf16 GEMM, XOR-swizzled LDS, fused LoRA + bias ----------
// LDS slot layout: 16B chunk (row, cc) of a tile lives at slot row*8 + (cc ^ (row&7)).
// Staging keeps the DMA dest (wave-uniform base + lane*16) and permutes the SOURCE.
__global__ __launch_bounds__(256, 4) void lora_gemm(
    const unsigned short* __restrict__ x,   // [M,K] bf16
    const unsigned short* __restrict__ W,   // [N,K] bf16
    const float* __restrict__ bias,         // [N] fp32
    const unsigned short* __restrict__ Bl,  // [N,16] bf16
    const unsigned short* __restrict__ xa,  // [M,16] bf16 (prescaled)
    float* __restrict__ out) {              // [M,N] fp32
    __shared__ __align__(16) unsigned short lA[BM * BK];
    __shared__ __align__(16) unsigned short lB[BN * BK];

    const int bn = blockIdx.x * BN;
    const int bm = blockIdx.y * BM;
    const int t = threadIdx.x;
    const int lane = t & 63;
    const int wave = t >> 6;
    const int wm = (wave >> 1) * 64;
    const int wn = (wave & 1) * 64;
    const int fr = lane & 15;
    const int fq = lane >> 4;
    const int f7 = fr & 7;

    // Per-lane source permutation for swizzled staging:
    const int srow = lane >> 3;                    // row-within-8 of this lane's slot
    const int scc = (lane & 7) ^ srow;             // swizzled k-chunk to fetch

    floatx4 acc[4][4];
#pragma unroll
    for (int i = 0; i < 4; ++i)
#pragma unroll
        for (int j = 0; j < 4; ++j)
            acc[i][j] = (floatx4){0.f, 0.f, 0.f, 0.f};

    // LoRA delta first: one rank-16 MFMA step, fragments direct from global,
    // zero-padded to K=32 in registers (fq>=2 lanes hold zeros).
    {
        bf16x8 z = {0, 0, 0, 0, 0, 0, 0, 0};
        bf16x8 af[4], bfv[4];
#pragma unroll
        for (int i = 0; i < 4; ++i) {
            int row = bm + wm + i * 16 + fr;
            af[i] = (fq < 2) ? *(const bf16x8*)(xa + (size_t)row * 16 + fq * 8) : z;
        }
#pragma unroll
        for (int j = 0; j < 4; ++j) {
            int row = bn + wn + j * 16 + fr;
            bfv[j] = (fq < 2) ? *(const bf16x8*)(Bl + (size_t)row * 16 + fq * 8) : z;
        }
#pragma unroll
        for (int i = 0; i < 4; ++i)
#pragma unroll
            for (int j = 0; j < 4; ++j)
                acc[i][j] = __builtin_amdgcn_mfma_f32_16x16x32_bf16(af[i], bfv[j], acc[i][j], 0, 0, 0);
    }

    for (int k0 = 0; k0 < KDIM; k0 += BK) {
#pragma unroll
        for (int i = 0; i < 4; ++i) {
            int cbase = i * 256 + wave * 64;           // slot base (wave-uniform)
            int row = (cbase >> 3) + srow;             // this lane's tile row
            __builtin_amdgcn_global_load_lds(
                (const __attribute__((address_space(1))) unsigned int*)(x + (size_t)(bm + row) * KDIM + k0 + scc * 8),
                (__attribute__((address_space(3))) unsigned int*)&lA[cbase * 8], 16, 0, 0);
            __builtin_amdgcn_global_load_lds(
                (const __attribute__((address_space(1))) unsigned int*)(W + (size_t)(bn + row) * KDIM + k0 + scc * 8),
                (__attribute__((address_space(3))) unsigned int*)&lB[cbase * 8], 16, 0, 0);
        }
        __syncthreads();

#pragma unroll
        for (int kk = 0; kk < BK; kk += 32) {
            const int jb = kk >> 3;                    // base chunk index (0 or 4)
            bf16x8 af[4], bfv[4];
#pragma unroll
            for (int i = 0; i < 4; ++i) {
                int r = wm + i * 16 + fr;
                af[i] = *(const bf16x8*)&lA[r * BK + (((jb + fq) ^ f7) << 3)];
            }
#pragma unroll
            for (int j = 0; j < 4; ++j) {
                int r = wn + j * 16 + fr;
                bfv[j] = *(const bf16x8*)&lB[r * BK + (((jb + fq) ^ f7) << 3)];
            }
#pragma unroll
            for (int i = 0; i < 4; ++i)
#pragma unroll
                for (int j = 0; j < 4; ++j)
                    acc[i][j] = __builtin_amdgcn_mfma_f32_16x16x32_bf16(af[i], bfv[j], acc[i][j], 0, 0, 0);
        }
        __syncthreads();
    }

    // Epilogue: D layout col=lane&15, row=(lane>>4)*4+reg. Add fp32 bias, store fp32.
#pragma unroll
    for (int j = 0; j < 4; ++j) {
        int col = bn + wn + j * 16 + fr;
        float bv = bias[col];
#pragma unroll
        for (int i = 0; i < 4; ++i) {
            int row0 = bm + wm + i * 16 + fq * 4;
#pragma unroll
            for (int r = 0; r < 4; ++r) {
                out[(size_t)(row0 + r) * NDIM + col] = acc[i][j][r] + bv;
            }
        }
    }
}

extern "C" void kernel_launch(void* const* d_in, const int* in_sizes, int n_in,
                              void* d_out, int out_size, void* d_ws, size_t ws_size,
                              hipStream_t stream) {
    const float* x    = (const float*)d_in[0];  // [4,2048,4096] fp32
    const float* W    = (const float*)d_in[1];  // [4096,4096] fp32
    const float* bias = (const float*)d_in[2];  // [4096] fp32
    const float* A    = (const float*)d_in[3];  // [16,4096] fp32
    const float* Bf   = (const float*)d_in[4];  // [4096,16] fp32
    float* out = (float*)d_out;                 // [8192,4096] fp32

    unsigned short* xc = (unsigned short*)d_ws;              // 64 MB
    unsigned short* Wc = xc + (size_t)MDIM * KDIM;           // 32 MB
    unsigned short* xa = Wc + (size_t)NDIM * KDIM;           // 256 KB
    unsigned short* Bc = xa + (size_t)MDIM * 16;             // 128 KB

    cvt_bf16<<<8192, 256, 0, stream>>>(x, xc, (MDIM * KDIM) / 8);
    cvt_bf16<<<4096, 256, 0, stream>>>(W, Wc, (NDIM * KDIM) / 8);
    lora_xa<<<512, 256, 0, stream>>>(xc, A, Bf, xa, Bc);
    lora_gemm<<<dim3(NDIM / BN, MDIM / BM), 256, 0, stream>>>(xc, Wc, bias, Bc, xa, out);
}